// Round 1
// 1641.587 us; speedup vs baseline: 1.0163x; 1.0163x over previous
//
#include <hip/hip_runtime.h>
#include <math.h>

#define NN   16384      // total nodes
#define NE   262144     // edges (no self loops)
#define NB   64         // graphs
#define SEQT 256        // nodes per graph (= seq len)
#define DEP  64
#define DOUT 256        // = HID
#define G3   768        // 3*HID
#define GK   256        // GEMM K (always 256 here)
#define ECAP 32         // GCN edges staged per chunk

typedef _Float16 h2_t   __attribute__((ext_vector_type(2)));
typedef _Float16 f16x4  __attribute__((ext_vector_type(4)));
typedef _Float16 f16x8  __attribute__((ext_vector_type(8)));
typedef float    f32x4  __attribute__((ext_vector_type(4)));

static __device__ __forceinline__ h2_t pk(float a, float b) {
    return (h2_t)__builtin_amdgcn_cvt_pkrtz(a, b);
}

static __device__ __forceinline__ float fast_sigmoid(float v) {
    return __builtin_amdgcn_rcpf(1.f + __expf(-v));
}
static __device__ __forceinline__ float fast_tanh(float v) {
    return 1.f - 2.f * __builtin_amdgcn_rcpf(1.f + __expf(2.f * v));
}

// barrier with LDS-only drain (no vmcnt: in-flight global loads/stores cross)
static __device__ __forceinline__ void bar_lds() {
    asm volatile("s_waitcnt lgkmcnt(0)\n\ts_barrier" ::: "memory");
}

// ---------------------------------------------------------------------------
// degree / CSR build (deg zero-initialized by memset; holds RAW in-degree)
// ---------------------------------------------------------------------------
__global__ void k_count(const int* __restrict__ ei, int* deg) {
    int e = blockIdx.x * 256 + threadIdx.x;
    if (e < NE) atomicAdd(&deg[ei[NE + e]], 1);   // col = dst
}

__global__ __launch_bounds__(1024) void k_scan_offs(const int* __restrict__ deg,
                                                    int* __restrict__ offs,
                                                    float* __restrict__ dinv) {
    __shared__ int lds[1024];
    const int tid = threadIdx.x;
    const int v0 = tid * 16;
    int loc[16];
    int s = 0;
#pragma unroll
    for (int i = 0; i < 16; ++i) {
        int d = deg[v0 + i];                      // raw in-edges
        loc[i] = s;
        s += d;
        dinv[v0 + i] = rsqrtf((float)(d + 1));    // +1 self loop
    }
    lds[tid] = s;
    __syncthreads();
    for (int off = 1; off < 1024; off <<= 1) {
        int x = (tid >= off) ? lds[tid - off] : 0;
        __syncthreads();
        lds[tid] += x;
        __syncthreads();
    }
    int base = lds[tid] - s;                      // exclusive prefix of this thread
#pragma unroll
    for (int i = 0; i < 16; ++i) offs[v0 + i] = base + loc[i];
}

__global__ void k_fill(const int* __restrict__ ei, const int* __restrict__ offs,
                       int* cursor, int* __restrict__ eidx) {
    int e = blockIdx.x * 256 + threadIdx.x;
    if (e < NE) {
        int c = ei[NE + e];
        int pos = offs[c] + atomicAdd(&cursor[c], 1);
        eidx[pos] = e;
    }
}

__global__ void k_bself(const float* __restrict__ WB, float* Bself) {
    int f = threadIdx.x;                          // 256 threads
    float s = 0.f;
#pragma unroll
    for (int d = 0; d < DEP; ++d) s += WB[f * DEP + d];
    Bself[f] = s;
}

// bias fold: bias768[l][j] = b_ih[j] + (j<512 ? b_hh[j] : 0)   (b_hn stays
// separate: the reference scales it by r before adding)
__global__ void k_bias_fold(const float* __restrict__ bi0, const float* __restrict__ bh0,
                            const float* __restrict__ bi1, const float* __restrict__ bh1,
                            const float* __restrict__ bi2, const float* __restrict__ bh2,
                            float* __restrict__ o) {
    int j = blockIdx.x * 256 + threadIdx.x;       // 9 blocks x 256 = 2304
    int l = j / G3, r = j % G3;
    const float* bi = (l == 0) ? bi0 : (l == 1) ? bi1 : bi2;
    const float* bh = (l == 0) ? bh0 : (l == 1) ? bh1 : bh2;
    o[j] = bi[r] + (r < 512 ? bh[r] : 0.f);
}

// ---------------------------------------------------------------------------
// one fused fp32->f16 conversion over all 5 regions
// ---------------------------------------------------------------------------
__global__ void k_cvt_all(const float* __restrict__ x,  const float* __restrict__ wa,
                          const float* __restrict__ w0, const float* __restrict__ w1,
                          const float* __restrict__ w2,
                          _Float16* __restrict__ xo,  _Float16* __restrict__ wao,
                          _Float16* __restrict__ w0o, _Float16* __restrict__ w1o,
                          _Float16* __restrict__ w2o) {
    size_t i = ((size_t)blockIdx.x * 256 + threadIdx.x) * 4;
    const size_t B0 = 4194304, B1 = B0 + 65536, B2 = B1 + 196608, B3 = B2 + 196608;
    const float* in; _Float16* out; size_t off;
    if      (i < B0) { in = x;  out = xo;  off = i; }
    else if (i < B1) { in = wa; out = wao; off = i - B0; }
    else if (i < B2) { in = w0; out = w0o; off = i - B1; }
    else if (i < B3) { in = w1; out = w1o; off = i - B2; }
    else             { in = w2; out = w2o; off = i - B3; }
    float4 v = *(const float4*)(in + off);
    *(h2_t*)(out + off)     = pk(v.x, v.y);
    *(h2_t*)(out + off + 2) = pk(v.z, v.w);
}

// ---------------------------------------------------------------------------
// MFMA f16 GEMM: C[M,N] = A16[M,256] @ B16[N,256]^T (+ bias).
// F16OUT: store f16 (used for xp); else fp32 (used for Ax).
// ---------------------------------------------------------------------------
template <bool F16OUT>
__global__ __launch_bounds__(256) void k_gemm16(const _Float16* __restrict__ A16,
                                                const _Float16* __restrict__ B16,
                                                const float* __restrict__ bias,
                                                void* __restrict__ Cout,
                                                int M, int N) {
    const int tid  = threadIdx.x;
    const int lane = tid & 63;
    const int wv   = tid >> 6;
    const int m0   = blockIdx.x * 128 + wv * 32;
    const int n0   = blockIdx.y * 128;
    const int ml   = lane & 15;
    const int quad = lane >> 4;

    const _Float16* ap0 = A16 + (size_t)(m0 + ml) * GK + quad * 8;
    const _Float16* ap1 = ap0 + (size_t)16 * GK;
    const _Float16* bp0 = B16 + (size_t)(n0 + ml) * GK + quad * 8;

    f32x4 acc[2][8];
#pragma unroll
    for (int i = 0; i < 2; ++i)
#pragma unroll
        for (int j = 0; j < 8; ++j) acc[i][j] = (f32x4){0.f, 0.f, 0.f, 0.f};

#pragma unroll 2
    for (int k0 = 0; k0 < GK; k0 += 32) {
        f16x8 a0 = *(const f16x8*)(ap0 + k0);
        f16x8 a1 = *(const f16x8*)(ap1 + k0);
#pragma unroll
        for (int nf = 0; nf < 8; ++nf) {
            f16x8 bf = *(const f16x8*)(bp0 + (size_t)nf * 16 * GK + k0);
            acc[0][nf] = __builtin_amdgcn_mfma_f32_16x16x32_f16(a0, bf, acc[0][nf], 0, 0, 0);
            acc[1][nf] = __builtin_amdgcn_mfma_f32_16x16x32_f16(a1, bf, acc[1][nf], 0, 0, 0);
        }
    }

#pragma unroll
    for (int mf = 0; mf < 2; ++mf)
#pragma unroll
        for (int nf = 0; nf < 8; ++nf) {
            const int col = n0 + nf * 16 + ml;
            const float bv = bias ? bias[col] : 0.f;
#pragma unroll
            for (int r = 0; r < 4; ++r) {
                const int row = m0 + mf * 16 + quad * 4 + r;
                float v = acc[mf][nf][r] + bv;
                if (F16OUT)
                    ((_Float16*)Cout)[(size_t)row * N + col] = (_Float16)v;
                else
                    ((float*)Cout)[(size_t)row * N + col] = v;
            }
        }
}

// ---------------------------------------------------------------------------
// GCN gather v2: chunked LDS staging, fast_tanh.
// ---------------------------------------------------------------------------
__global__ __launch_bounds__(256) void k_gcn(const float* __restrict__ Ax,
                                             const float* __restrict__ WB,
                                             const float* __restrict__ edge_attr,
                                             const int* __restrict__ ei,
                                             const int* __restrict__ eidx,
                                             const int* __restrict__ offs,
                                             const int* __restrict__ deg,
                                             const float* __restrict__ dinv,
                                             const float* __restrict__ Bself,
                                             const float* __restrict__ gcn_bias,
                                             _Float16* __restrict__ node16) {
    const int v = blockIdx.x;
    const int f = threadIdx.x;

    float wb[64];
#pragma unroll
    for (int d4 = 0; d4 < 16; ++d4) {
        float4 t = *(const float4*)&WB[f * DEP + d4 * 4];
        wb[d4 * 4 + 0] = t.x; wb[d4 * 4 + 1] = t.y;
        wb[d4 * 4 + 2] = t.z; wb[d4 * 4 + 3] = t.w;
    }

    __shared__ float ea_s[ECAP * 64];
    __shared__ int   es_s[ECAP];
    __shared__ int   src_s[ECAP];
    __shared__ float nrm_s[ECAP];

    const int   base = offs[v];
    const int   cnt  = deg[v];                   // raw in-edges
    const float dv   = dinv[v];
    float acc = 0.f;

    for (int c0 = 0; c0 < cnt; c0 += ECAP) {
        const int n = min(ECAP, cnt - c0);
        if (f < n) {
            int e = eidx[base + c0 + f];
            es_s[f] = e;
            int s = ei[e];
            src_s[f] = s;
            nrm_s[f] = dinv[s] * dv;
        }
        __syncthreads();
        for (int idx = f; idx < n * 64; idx += 256) {
            int el = idx >> 6, d = idx & 63;
            ea_s[idx] = edge_attr[(size_t)es_s[el] * DEP + d];
        }
        __syncthreads();
        for (int i = 0; i < n; ++i) {
            float ax = Ax[(size_t)src_s[i] * DOUT + f];   // issued early
            float be = 0.f;
#pragma unroll
            for (int d = 0; d < 64; ++d) be = fmaf(wb[d], ea_s[i * 64 + d], be);
            acc = fmaf(nrm_s[i], fast_tanh(ax * be), acc);
        }
        __syncthreads();                          // before chunk overwrite
    }
    // self loop: norm = dinv^2, Be = rowsum(WB)
    acc += dv * dv * fast_tanh(Ax[(size_t)v * DOUT + f] * Bself[f]);
    float nv = fast_tanh(acc / (float)(cnt + 1) + gcn_bias[f]);
    node16[(size_t)v * DOUT + f] = (_Float16)nv;
}

// ---------------------------------------------------------------------------
// GRU scan v9: wave-local gates, ONE barrier per step.
//
// Old structure (v8, 383 us): MFMA all waves -> barrier -> gates on waves 0-3
// (waves 4-7 + MFMA pipe idle) -> barrier.  Per-step 3590 cyc; MFMA pipe only
// ~1860 of them (43% active-CU MfmaUtil).
//
// v9: w_hh rows are PERMUTED at A-frag load time so wave wv computes exactly
// gh rows {j, 256+j, 512+j : j in [32*wv, 32*wv+32)} -- all three gate
// components for its own 32 hidden units.  (C-frag cols are 16 identical
// copies of the matvec, so every lane holds every row of its fragment.)
// gh then lives in a wave-PRIVATE 96-float LDS scratch: write -> lgkmcnt(0)
// (same-wave DS ops are in-order) -> read; no barrier, no cross-wave dep.
// Each wave computes gates for its 32 j's (lanes 0-31; 32-63 duplicate) and
// writes its h slice.  Only ONE barrier/step remains (publish h(t+1),
// double-buffered).  h itself is NOT permuted: xp/GEMM/y16 layouts unchanged.
// ---------------------------------------------------------------------------
__global__ __launch_bounds__(512, 2) void k_gru_scan(const _Float16* __restrict__ xp16,
                                                     const float* __restrict__ w_hh,
                                                     const float* __restrict__ b_hh,
                                                     _Float16* __restrict__ y16,
                                                     float* __restrict__ hT_all,
                                                     int layer,
                                                     const float* __restrict__ lin_W,
                                                     const float* __restrict__ lin_b,
                                                     float* __restrict__ out) {
    const int tid  = threadIdx.x;
    const int b    = blockIdx.x;                 // graph
    const int lane = tid & 63;
    const int wv   = tid >> 6;                   // wave 0..7
    const int m    = lane & 15;                  // A-frag row within 16
    const int quad = lane >> 4;                  // 0..3 (k-subgroup)
    const int jl   = lane & 31;                  // gate slot within wave
    const int j    = wv * 32 + jl;               // hidden unit this lane gates
    const bool gl  = lane < 32;                  // lanes 32-63 duplicate jl

    // --- weights -> A-fragments (one-time global read, fp32 -> f16) ---
    // local row lr = rb*16 + m; global w_hh row = 256*(lr/32) + 32*wv + lr%32
    // => frags 0-1 are the r-gate rows for this wave's j's, 2-3 z, 4-5 n.
    f16x8 A[6][8];
#pragma unroll
    for (int rb = 0; rb < 6; ++rb) {
        const int lr  = rb * 16 + m;
        const int row = ((lr >> 5) << 8) + wv * 32 + (lr & 31);
#pragma unroll
        for (int kt = 0; kt < 8; ++kt) {
            const float* wp = w_hh + (size_t)row * 256 + kt * 32 + quad * 8;
            float4 a0 = *(const float4*)wp;
            float4 a1 = *(const float4*)(wp + 4);
            union { f16x8 v; h2_t h[4]; } u;
            u.h[0] = pk(a0.x, a0.y); u.h[1] = pk(a0.z, a0.w);
            u.h[2] = pk(a1.x, a1.y); u.h[3] = pk(a1.z, a1.w);
            A[rb][kt] = u.v;
        }
    }

    const float bhn = b_hh[512 + j];             // n-gate hidden bias (r/z folded)

    __shared__ _Float16 h16[2][256];             // h(t) f16, double-buffered
    __shared__ float    ghW_all[8][96];          // per-wave PRIVATE gh scratch
    __shared__ float    pool[1280];              // layer-2 epilogue only
    __shared__ float    red[512];
    float* const ghW = ghW_all[wv];

    float h_old = 0.f;                           // gl lane owns h[j]
    if (tid < 256) h16[0][tid] = (_Float16)0.f;
    __syncthreads();

    const _Float16* xpb  = xp16 + (size_t)b * SEQT * G3;
    _Float16*       yb16 = y16  + (size_t)b * SEQT * DOUT;

    float mx = -1e30f, sm = 0.f;                 // layer-2 pooling accum

    for (int t = 0; t < SEQT; ++t) {
        // prefetch this step's xp (f16; consumed ~full MFMA phase later)
        const _Float16* xpt = xpb + (size_t)t * G3;
        const float xr = (float)xpt[j];
        const float xz = (float)xpt[256 + j];
        const float xn = (float)xpt[512 + j];

        // k-outer MFMA: one B-frag per kt feeds 6 independent chains
        const _Float16* hcur = h16[t & 1];
        f32x4 C[6];
#pragma unroll
        for (int rb = 0; rb < 6; ++rb) C[rb] = (f32x4){0.f, 0.f, 0.f, 0.f};

        union { f16x8 v; float4 f; } Bk, Bn;
        Bk.f = *(const float4*)&hcur[quad * 8];
#pragma unroll
        for (int kt = 0; kt < 8; ++kt) {
            if (kt < 7) Bn.f = *(const float4*)&hcur[(kt + 1) * 32 + quad * 8];
#pragma unroll
            for (int rb = 0; rb < 6; ++rb)
                C[rb] = __builtin_amdgcn_mfma_f32_16x16x32_f16(A[rb][kt], Bk.v, C[rb], 0, 0, 0);
            Bk.v = Bn.v;
        }

        // wave-local gh publish: 4 lanes (m==0, one per quad) cover all 96 rows
        if (m == 0) {
#pragma unroll
            for (int rb = 0; rb < 6; ++rb)
                *(f32x4*)&ghW[rb * 16 + quad * 4] = C[rb];
        }
        // same-wave DS ops complete in-order; drain writes before the reads
        asm volatile("s_waitcnt lgkmcnt(0)" ::: "memory");

        // gates for this wave's own 32 j's (no cross-wave dependency)
        const float r  = fast_sigmoid(xr + ghW[jl]);
        const float z  = fast_sigmoid(xz + ghW[32 + jl]);
        const float n  = fast_tanh(xn + r * (ghW[64 + jl] + bhn));
        const float hn = (1.f - z) * n + z * h_old;
        h_old = hn;
        if (gl) {
            h16[(t & 1) ^ 1][j] = (_Float16)hn;  // next step's buffer
            if (layer < 2) {
                yb16[(size_t)t * DOUT + j] = (_Float16)hn;
                if (t == SEQT - 1) hT_all[layer * NB * 256 + b * 256 + j] = hn;
            }
        }
        if (layer == 2) { mx = fmaxf(mx, hn); sm += hn; }

        bar_lds();                               // the ONLY per-step barrier
    }

    if (layer == 2) {
        // --- fused pooling + linear + softmax ---
        if (gl) {
            pool[j]        = hT_all[b * 256 + j];               // layer-0 hT
            pool[256 + j]  = hT_all[NB * 256 + b * 256 + j];    // layer-1 hT
            pool[512 + j]  = h_old;                             // layer-2 hT
            pool[768 + j]  = mx;
            pool[1024 + j] = sm * (1.f / 256.f);
        }
        __syncthreads();
        if (tid < 256) {
            float p0 = 0.f, p1 = 0.f;
            for (int i = tid; i < 1280; i += 256) {
                float pv = pool[i];
                p0 = fmaf(lin_W[i], pv, p0);
                p1 = fmaf(lin_W[1280 + i], pv, p1);
            }
            red[tid] = p0; red[256 + tid] = p1;
        }
        __syncthreads();
        if (tid == 0) {
            float l0 = lin_b[0], l1 = lin_b[1];
            for (int i = 0; i < 256; ++i) { l0 += red[i]; l1 += red[256 + i]; }
            float m2 = fmaxf(l0, l1);
            float e0 = __expf(l0 - m2), e1 = __expf(l1 - m2);
            float s = e0 + e1;
            out[b * 2 + 0] = e0 / s;
            out[b * 2 + 1] = e1 / s;
        }
    }
}

// ---------------------------------------------------------------------------
extern "C" void kernel_launch(void* const* d_in, const int* in_sizes, int n_in,
                              void* d_out, int out_size, void* d_ws, size_t ws_size,
                              hipStream_t stream) {
    const float* x         = (const float*)d_in[0];
    const float* edge_attr = (const float*)d_in[1];
    const int*   ei        = (const int*)d_in[2];
    const float* WA        = (const float*)d_in[3];
    const float* WB        = (const float*)d_in[4];
    const float* gcn_bias  = (const float*)d_in[5];
    const float* w_ih[3] = {(const float*)d_in[6],  (const float*)d_in[10], (const float*)d_in[14]};
    const float* w_hh[3] = {(const float*)d_in[7],  (const float*)d_in[11], (const float*)d_in[15]};
    const float* b_ih[3] = {(const float*)d_in[8],  (const float*)d_in[12], (const float*)d_in[16]};
    const float* b_hh[3] = {(const float*)d_in[9],  (const float*)d_in[13], (const float*)d_in[17]};
    const float* lin_W = (const float*)d_in[18];
    const float* lin_b = (const float*)d_in[19];
    float* out = (float*)d_out;

    char* p = (char*)d_ws;
    auto alloc = [&](size_t bytes) {
        char* r = p;
        p += (bytes + 255) & ~(size_t)255;
        return r;
    };
    int*   deg    = (int*)alloc((size_t)NN * 4);   // ┐ contiguous: one memset
    int*   offs   = (int*)alloc((size_t)NN * 4);   // │
    int*   cursor = (int*)alloc((size_t)NN * 4);   // ┘
    float* dinv   = (float*)alloc((size_t)NN * 4);
    int*   eidx   = (int*)alloc((size_t)NE * 4);
    float* Bself  = (float*)alloc(256 * 4);
    float* hT     = (float*)alloc(2 * NB * 256 * 4);
    float* bias768 = (float*)alloc(3 * G3 * 4);
    float* Ax     = (float*)alloc((size_t)NN * DOUT * 4);
    _Float16* xp16 = (_Float16*)alloc((size_t)NN * G3 * 2);

    _Float16* node16 = (_Float16*)alloc((size_t)NN * DOUT * 2);
    _Float16* yA16   = (_Float16*)alloc((size_t)NN * DOUT * 2);
    _Float16* x16    = (_Float16*)alloc((size_t)NN * DOUT * 2);
    _Float16* yB16   = x16;  // alias: x16 dead after Ax GEMM, yB16 live later
    _Float16* WA16   = (_Float16*)alloc((size_t)256 * 256 * 2);
    _Float16* wih16[3];
    for (int l = 0; l < 3; ++l) wih16[l] = (_Float16*)alloc((size_t)G3 * 256 * 2);

    // --- CSR build + weight conversions + bias fold ---
    hipMemsetAsync(deg, 0, (size_t)3 * NN * 4, stream);    // deg+offs+cursor
    k_count<<<NE / 256, 256, 0, stream>>>(ei, deg);
    k_scan_offs<<<1, 1024, 0, stream>>>(deg, offs, dinv);
    k_fill<<<NE / 256, 256, 0, stream>>>(ei, offs, cursor, eidx);
    k_bself<<<1, 256, 0, stream>>>(WB, Bself);
    k_bias_fold<<<9, 256, 0, stream>>>(b_ih[0], b_hh[0], b_ih[1], b_hh[1],
                                       b_ih[2], b_hh[2], bias768);
    k_cvt_all<<<4736, 256, 0, stream>>>(x, WA, w_ih[0], w_ih[1], w_ih[2],
                                        x16, WA16, wih16[0], wih16[1], wih16[2]);

    // --- GCN ---
    {
        dim3 g(NN / 128, 256 / 128);
        k_gemm16<false><<<g, 256, 0, stream>>>(x16, WA16, nullptr, Ax, NN, 256);
    }
    k_gcn<<<NN, 256, 0, stream>>>(Ax, WB, edge_attr, ei, eidx, offs, deg, dinv,
                                  Bself, gcn_bias, node16);

    // --- GRU x3 (layer 2 fuses pooling+linear+softmax) ---
    const _Float16* in16 = node16;
    _Float16* y16_outs[3] = {yA16, yB16, yA16};
    for (int l = 0; l < 3; ++l) {
        dim3 g(NN / 128, G3 / 128);
        k_gemm16<true><<<g, 256, 0, stream>>>(in16, wih16[l], bias768 + l * G3,
                                              xp16, NN, G3);
        k_gru_scan<<<NB, 512, 0, stream>>>(xp16, w_hh[l], b_hh[l], y16_outs[l],
                                           hT, l, lin_W, lin_b, out);
        in16 = y16_outs[l];
    }
}

// Round 2
// 1638.502 us; speedup vs baseline: 1.0182x; 1.0019x over previous
//
#include <hip/hip_runtime.h>
#include <math.h>

#define NN   16384      // total nodes
#define NE   262144     // edges (no self loops)
#define NB   64         // graphs
#define SEQT 256        // nodes per graph (= seq len)
#define DEP  64
#define DOUT 256        // = HID
#define G3   768        // 3*HID
#define GK   256        // GEMM K (always 256 here)
#define ECAP 32         // GCN edges staged per chunk

typedef _Float16 h2_t   __attribute__((ext_vector_type(2)));
typedef _Float16 f16x4  __attribute__((ext_vector_type(4)));
typedef _Float16 f16x8  __attribute__((ext_vector_type(8)));
typedef float    f32x4  __attribute__((ext_vector_type(4)));

static __device__ __forceinline__ h2_t pk(float a, float b) {
    return (h2_t)__builtin_amdgcn_cvt_pkrtz(a, b);
}

static __device__ __forceinline__ float fast_sigmoid(float v) {
    return __builtin_amdgcn_rcpf(1.f + __expf(-v));
}
static __device__ __forceinline__ float fast_tanh(float v) {
    return 1.f - 2.f * __builtin_amdgcn_rcpf(1.f + __expf(2.f * v));
}

// barrier with LDS-only drain (no vmcnt: in-flight global loads/stores cross)
static __device__ __forceinline__ void bar_lds() {
    asm volatile("s_waitcnt lgkmcnt(0)\n\ts_barrier" ::: "memory");
}

// ---------------------------------------------------------------------------
// degree / CSR build (deg zero-initialized by memset; holds RAW in-degree)
// ---------------------------------------------------------------------------
__global__ void k_count(const int* __restrict__ ei, int* deg) {
    int e = blockIdx.x * 256 + threadIdx.x;
    if (e < NE) atomicAdd(&deg[ei[NE + e]], 1);   // col = dst
}

__global__ __launch_bounds__(1024) void k_scan_offs(const int* __restrict__ deg,
                                                    int* __restrict__ offs,
                                                    float* __restrict__ dinv) {
    __shared__ int lds[1024];
    const int tid = threadIdx.x;
    const int v0 = tid * 16;
    int loc[16];
    int s = 0;
#pragma unroll
    for (int i = 0; i < 16; ++i) {
        int d = deg[v0 + i];                      // raw in-edges
        loc[i] = s;
        s += d;
        dinv[v0 + i] = rsqrtf((float)(d + 1));    // +1 self loop
    }
    lds[tid] = s;
    __syncthreads();
    for (int off = 1; off < 1024; off <<= 1) {
        int x = (tid >= off) ? lds[tid - off] : 0;
        __syncthreads();
        lds[tid] += x;
        __syncthreads();
    }
    int base = lds[tid] - s;                      // exclusive prefix of this thread
#pragma unroll
    for (int i = 0; i < 16; ++i) offs[v0 + i] = base + loc[i];
}

__global__ void k_fill(const int* __restrict__ ei, const int* __restrict__ offs,
                       int* cursor, int* __restrict__ eidx) {
    int e = blockIdx.x * 256 + threadIdx.x;
    if (e < NE) {
        int c = ei[NE + e];
        int pos = offs[c] + atomicAdd(&cursor[c], 1);
        eidx[pos] = e;
    }
}

__global__ void k_bself(const float* __restrict__ WB, float* Bself) {
    int f = threadIdx.x;                          // 256 threads
    float s = 0.f;
#pragma unroll
    for (int d = 0; d < DEP; ++d) s += WB[f * DEP + d];
    Bself[f] = s;
}

// bias fold: bias768[l][j] = b_ih[j] + (j<512 ? b_hh[j] : 0)   (b_hn stays
// separate: the reference scales it by r before adding)
__global__ void k_bias_fold(const float* __restrict__ bi0, const float* __restrict__ bh0,
                            const float* __restrict__ bi1, const float* __restrict__ bh1,
                            const float* __restrict__ bi2, const float* __restrict__ bh2,
                            float* __restrict__ o) {
    int j = blockIdx.x * 256 + threadIdx.x;       // 9 blocks x 256 = 2304
    int l = j / G3, r = j % G3;
    const float* bi = (l == 0) ? bi0 : (l == 1) ? bi1 : bi2;
    const float* bh = (l == 0) ? bh0 : (l == 1) ? bh1 : bh2;
    o[j] = bi[r] + (r < 512 ? bh[r] : 0.f);
}

// ---------------------------------------------------------------------------
// one fused fp32->f16 conversion over all 5 regions
// ---------------------------------------------------------------------------
__global__ void k_cvt_all(const float* __restrict__ x,  const float* __restrict__ wa,
                          const float* __restrict__ w0, const float* __restrict__ w1,
                          const float* __restrict__ w2,
                          _Float16* __restrict__ xo,  _Float16* __restrict__ wao,
                          _Float16* __restrict__ w0o, _Float16* __restrict__ w1o,
                          _Float16* __restrict__ w2o) {
    size_t i = ((size_t)blockIdx.x * 256 + threadIdx.x) * 4;
    const size_t B0 = 4194304, B1 = B0 + 65536, B2 = B1 + 196608, B3 = B2 + 196608;
    const float* in; _Float16* out; size_t off;
    if      (i < B0) { in = x;  out = xo;  off = i; }
    else if (i < B1) { in = wa; out = wao; off = i - B0; }
    else if (i < B2) { in = w0; out = w0o; off = i - B1; }
    else if (i < B3) { in = w1; out = w1o; off = i - B2; }
    else             { in = w2; out = w2o; off = i - B3; }
    float4 v = *(const float4*)(in + off);
    *(h2_t*)(out + off)     = pk(v.x, v.y);
    *(h2_t*)(out + off + 2) = pk(v.z, v.w);
}

// ---------------------------------------------------------------------------
// MFMA f16 GEMM: C[M,N] = A16[M,256] @ B16[N,256]^T (+ bias).
// F16OUT: store f16 (used for xp); else fp32 (used for Ax).
// ---------------------------------------------------------------------------
template <bool F16OUT>
__global__ __launch_bounds__(256) void k_gemm16(const _Float16* __restrict__ A16,
                                                const _Float16* __restrict__ B16,
                                                const float* __restrict__ bias,
                                                void* __restrict__ Cout,
                                                int M, int N) {
    const int tid  = threadIdx.x;
    const int lane = tid & 63;
    const int wv   = tid >> 6;
    const int m0   = blockIdx.x * 128 + wv * 32;
    const int n0   = blockIdx.y * 128;
    const int ml   = lane & 15;
    const int quad = lane >> 4;

    const _Float16* ap0 = A16 + (size_t)(m0 + ml) * GK + quad * 8;
    const _Float16* ap1 = ap0 + (size_t)16 * GK;
    const _Float16* bp0 = B16 + (size_t)(n0 + ml) * GK + quad * 8;

    f32x4 acc[2][8];
#pragma unroll
    for (int i = 0; i < 2; ++i)
#pragma unroll
        for (int j = 0; j < 8; ++j) acc[i][j] = (f32x4){0.f, 0.f, 0.f, 0.f};

#pragma unroll 2
    for (int k0 = 0; k0 < GK; k0 += 32) {
        f16x8 a0 = *(const f16x8*)(ap0 + k0);
        f16x8 a1 = *(const f16x8*)(ap1 + k0);
#pragma unroll
        for (int nf = 0; nf < 8; ++nf) {
            f16x8 bf = *(const f16x8*)(bp0 + (size_t)nf * 16 * GK + k0);
            acc[0][nf] = __builtin_amdgcn_mfma_f32_16x16x32_f16(a0, bf, acc[0][nf], 0, 0, 0);
            acc[1][nf] = __builtin_amdgcn_mfma_f32_16x16x32_f16(a1, bf, acc[1][nf], 0, 0, 0);
        }
    }

#pragma unroll
    for (int mf = 0; mf < 2; ++mf)
#pragma unroll
        for (int nf = 0; nf < 8; ++nf) {
            const int col = n0 + nf * 16 + ml;
            const float bv = bias ? bias[col] : 0.f;
#pragma unroll
            for (int r = 0; r < 4; ++r) {
                const int row = m0 + mf * 16 + quad * 4 + r;
                float v = acc[mf][nf][r] + bv;
                if (F16OUT)
                    ((_Float16*)Cout)[(size_t)row * N + col] = (_Float16)v;
                else
                    ((float*)Cout)[(size_t)row * N + col] = v;
            }
        }
}

// ---------------------------------------------------------------------------
// GCN gather v2: chunked LDS staging, fast_tanh.
// ---------------------------------------------------------------------------
__global__ __launch_bounds__(256) void k_gcn(const float* __restrict__ Ax,
                                             const float* __restrict__ WB,
                                             const float* __restrict__ edge_attr,
                                             const int* __restrict__ ei,
                                             const int* __restrict__ eidx,
                                             const int* __restrict__ offs,
                                             const int* __restrict__ deg,
                                             const float* __restrict__ dinv,
                                             const float* __restrict__ Bself,
                                             const float* __restrict__ gcn_bias,
                                             _Float16* __restrict__ node16) {
    const int v = blockIdx.x;
    const int f = threadIdx.x;

    float wb[64];
#pragma unroll
    for (int d4 = 0; d4 < 16; ++d4) {
        float4 t = *(const float4*)&WB[f * DEP + d4 * 4];
        wb[d4 * 4 + 0] = t.x; wb[d4 * 4 + 1] = t.y;
        wb[d4 * 4 + 2] = t.z; wb[d4 * 4 + 3] = t.w;
    }

    __shared__ float ea_s[ECAP * 64];
    __shared__ int   es_s[ECAP];
    __shared__ int   src_s[ECAP];
    __shared__ float nrm_s[ECAP];

    const int   base = offs[v];
    const int   cnt  = deg[v];                   // raw in-edges
    const float dv   = dinv[v];
    float acc = 0.f;

    for (int c0 = 0; c0 < cnt; c0 += ECAP) {
        const int n = min(ECAP, cnt - c0);
        if (f < n) {
            int e = eidx[base + c0 + f];
            es_s[f] = e;
            int s = ei[e];
            src_s[f] = s;
            nrm_s[f] = dinv[s] * dv;
        }
        __syncthreads();
        for (int idx = f; idx < n * 64; idx += 256) {
            int el = idx >> 6, d = idx & 63;
            ea_s[idx] = edge_attr[(size_t)es_s[el] * DEP + d];
        }
        __syncthreads();
        for (int i = 0; i < n; ++i) {
            float ax = Ax[(size_t)src_s[i] * DOUT + f];   // issued early
            float be = 0.f;
#pragma unroll
            for (int d = 0; d < 64; ++d) be = fmaf(wb[d], ea_s[i * 64 + d], be);
            acc = fmaf(nrm_s[i], fast_tanh(ax * be), acc);
        }
        __syncthreads();                          // before chunk overwrite
    }
    // self loop: norm = dinv^2, Be = rowsum(WB)
    acc += dv * dv * fast_tanh(Ax[(size_t)v * DOUT + f] * Bself[f]);
    float nv = fast_tanh(acc / (float)(cnt + 1) + gcn_bias[f]);
    node16[(size_t)v * DOUT + f] = (_Float16)nv;
}

// ---------------------------------------------------------------------------
// GRU scan v10: v9 (wave-local gates, one barrier/step) + xp REGISTER
// PREFETCH one full step ahead.
//
// v9 post-mortem: removing a barrier + gate-wave idleness gained only 2%
// (3590 -> 3515 cyc/step).  Per-step accounting at 2.4 GHz: MFMA pipe busy
// 1539 cyc (96 MFMA x 16 cyc/SIMD -- the structural floor), VALU ~730,
// unexplained idle ~1250.  Hypothesis: the three per-step xp16 loads get
// SUNK by the register allocator (A-frags pin ~192 regs) to just before the
// gate use -> exposed cold-HBM latency (~900 cyc) every step behind a
// vmcnt(0).
//
// v10: xp(t+1) is loaded into loop-carried f16 registers at the TOP of step
// t, before the MFMA phase.  Loop-carried values cannot be sunk; they get a
// full step (~3.5k cyc) of slack and stay in flight across bar_lds (which
// deliberately does not drain vmcnt).  kt-loop de-pipelined to straight
// line: the compiler hoists the 8 ds_read_b128 itself and drops the manual
// Bk/Bn v_mov rotation.
// ---------------------------------------------------------------------------
__global__ __launch_bounds__(512, 2) void k_gru_scan(const _Float16* __restrict__ xp16,
                                                     const float* __restrict__ w_hh,
                                                     const float* __restrict__ b_hh,
                                                     _Float16* __restrict__ y16,
                                                     float* __restrict__ hT_all,
                                                     int layer,
                                                     const float* __restrict__ lin_W,
                                                     const float* __restrict__ lin_b,
                                                     float* __restrict__ out) {
    const int tid  = threadIdx.x;
    const int b    = blockIdx.x;                 // graph
    const int lane = tid & 63;
    const int wv   = tid >> 6;                   // wave 0..7
    const int m    = lane & 15;                  // A-frag row within 16
    const int quad = lane >> 4;                  // 0..3 (k-subgroup)
    const int jl   = lane & 31;                  // gate slot within wave
    const int j    = wv * 32 + jl;               // hidden unit this lane gates
    const bool gl  = lane < 32;                  // lanes 32-63 duplicate jl

    // --- weights -> A-fragments (one-time global read, fp32 -> f16) ---
    // local row lr = rb*16 + m; global w_hh row = 256*(lr/32) + 32*wv + lr%32
    // => frags 0-1 are the r-gate rows for this wave's j's, 2-3 z, 4-5 n.
    f16x8 A[6][8];
#pragma unroll
    for (int rb = 0; rb < 6; ++rb) {
        const int lr  = rb * 16 + m;
        const int row = ((lr >> 5) << 8) + wv * 32 + (lr & 31);
#pragma unroll
        for (int kt = 0; kt < 8; ++kt) {
            const float* wp = w_hh + (size_t)row * 256 + kt * 32 + quad * 8;
            float4 a0 = *(const float4*)wp;
            float4 a1 = *(const float4*)(wp + 4);
            union { f16x8 v; h2_t h[4]; } u;
            u.h[0] = pk(a0.x, a0.y); u.h[1] = pk(a0.z, a0.w);
            u.h[2] = pk(a1.x, a1.y); u.h[3] = pk(a1.z, a1.w);
            A[rb][kt] = u.v;
        }
    }

    const float bhn = b_hh[512 + j];             // n-gate hidden bias (r/z folded)

    __shared__ _Float16 h16[2][256];             // h(t) f16, double-buffered
    __shared__ float    ghW_all[8][96];          // per-wave PRIVATE gh scratch
    __shared__ float    pool[1280];              // layer-2 epilogue only
    __shared__ float    red[512];
    float* const ghW = ghW_all[wv];

    float h_old = 0.f;                           // gl lane owns h[j]
    if (tid < 256) h16[0][tid] = (_Float16)0.f;
    __syncthreads();

    const _Float16* xpb  = xp16 + (size_t)b * SEQT * G3;
    _Float16*       yb16 = y16  + (size_t)b * SEQT * DOUT;

    float mx = -1e30f, sm = 0.f;                 // layer-2 pooling accum

    // prefetch xp(0) (loop-carried registers; re-issued each step for t+1)
    _Float16 pxr = xpb[j], pxz = xpb[256 + j], pxn = xpb[512 + j];

    for (int t = 0; t < SEQT; ++t) {
        // consume this step's prefetched xp (loads issued one step ago)
        const float xr = (float)pxr;
        const float xz = (float)pxz;
        const float xn = (float)pxn;
        // issue NEXT step's xp loads now -- they ride out the whole MFMA
        // phase + barrier (bar_lds has no vmcnt drain).  t=255 reads the
        // next graph's block / workspace tail: in-bounds, values unused.
        {
            const _Float16* xq = xpb + (size_t)(t + 1) * G3 + j;
            pxr = xq[0]; pxz = xq[256]; pxn = xq[512];
        }

        // k-outer MFMA: straight-line; compiler hoists the 8 ds_read_b128
        const _Float16* hcur = h16[t & 1];
        f32x4 C[6];
#pragma unroll
        for (int rb = 0; rb < 6; ++rb) C[rb] = (f32x4){0.f, 0.f, 0.f, 0.f};

#pragma unroll
        for (int kt = 0; kt < 8; ++kt) {
            union { f16x8 v; float4 f; } Bk;
            Bk.f = *(const float4*)&hcur[kt * 32 + quad * 8];
#pragma unroll
            for (int rb = 0; rb < 6; ++rb)
                C[rb] = __builtin_amdgcn_mfma_f32_16x16x32_f16(A[rb][kt], Bk.v, C[rb], 0, 0, 0);
        }

        // wave-local gh publish: 4 lanes (m==0, one per quad) cover all 96 rows
        if (m == 0) {
#pragma unroll
            for (int rb = 0; rb < 6; ++rb)
                *(f32x4*)&ghW[rb * 16 + quad * 4] = C[rb];
        }
        // same-wave DS ops complete in-order; drain writes before the reads
        asm volatile("s_waitcnt lgkmcnt(0)" ::: "memory");

        // gates for this wave's own 32 j's (no cross-wave dependency)
        const float r  = fast_sigmoid(xr + ghW[jl]);
        const float z  = fast_sigmoid(xz + ghW[32 + jl]);
        const float n  = fast_tanh(xn + r * (ghW[64 + jl] + bhn));
        const float hn = n + z * (h_old - n);
        h_old = hn;
        if (gl) {
            h16[(t & 1) ^ 1][j] = (_Float16)hn;  // next step's buffer
            if (layer < 2) {
                yb16[(size_t)t * DOUT + j] = (_Float16)hn;
                if (t == SEQT - 1) hT_all[layer * NB * 256 + b * 256 + j] = hn;
            }
        }
        if (layer == 2) { mx = fmaxf(mx, hn); sm += hn; }

        bar_lds();                               // the ONLY per-step barrier
    }

    if (layer == 2) {
        // --- fused pooling + linear + softmax ---
        if (gl) {
            pool[j]        = hT_all[b * 256 + j];               // layer-0 hT
            pool[256 + j]  = hT_all[NB * 256 + b * 256 + j];    // layer-1 hT
            pool[512 + j]  = h_old;                             // layer-2 hT
            pool[768 + j]  = mx;
            pool[1024 + j] = sm * (1.f / 256.f);
        }
        __syncthreads();
        if (tid < 256) {
            float p0 = 0.f, p1 = 0.f;
            for (int i = tid; i < 1280; i += 256) {
                float pv = pool[i];
                p0 = fmaf(lin_W[i], pv, p0);
                p1 = fmaf(lin_W[1280 + i], pv, p1);
            }
            red[tid] = p0; red[256 + tid] = p1;
        }
        __syncthreads();
        if (tid == 0) {
            float l0 = lin_b[0], l1 = lin_b[1];
            for (int i = 0; i < 256; ++i) { l0 += red[i]; l1 += red[256 + i]; }
            float m2 = fmaxf(l0, l1);
            float e0 = __expf(l0 - m2), e1 = __expf(l1 - m2);
            float s = e0 + e1;
            out[b * 2 + 0] = e0 / s;
            out[b * 2 + 1] = e1 / s;
        }
    }
}

// ---------------------------------------------------------------------------
extern "C" void kernel_launch(void* const* d_in, const int* in_sizes, int n_in,
                              void* d_out, int out_size, void* d_ws, size_t ws_size,
                              hipStream_t stream) {
    const float* x         = (const float*)d_in[0];
    const float* edge_attr = (const float*)d_in[1];
    const int*   ei        = (const int*)d_in[2];
    const float* WA        = (const float*)d_in[3];
    const float* WB        = (const float*)d_in[4];
    const float* gcn_bias  = (const float*)d_in[5];
    const float* w_ih[3] = {(const float*)d_in[6],  (const float*)d_in[10], (const float*)d_in[14]};
    const float* w_hh[3] = {(const float*)d_in[7],  (const float*)d_in[11], (const float*)d_in[15]};
    const float* b_ih[3] = {(const float*)d_in[8],  (const float*)d_in[12], (const float*)d_in[16]};
    const float* b_hh[3] = {(const float*)d_in[9],  (const float*)d_in[13], (const float*)d_in[17]};
    const float* lin_W = (const float*)d_in[18];
    const float* lin_b = (const float*)d_in[19];
    float* out = (float*)d_out;

    char* p = (char*)d_ws;
    auto alloc = [&](size_t bytes) {
        char* r = p;
        p += (bytes + 255) & ~(size_t)255;
        return r;
    };
    int*   deg    = (int*)alloc((size_t)NN * 4);   // ┐ contiguous: one memset
    int*   offs   = (int*)alloc((size_t)NN * 4);   // │
    int*   cursor = (int*)alloc((size_t)NN * 4);   // ┘
    float* dinv   = (float*)alloc((size_t)NN * 4);
    int*   eidx   = (int*)alloc((size_t)NE * 4);
    float* Bself  = (float*)alloc(256 * 4);
    float* hT     = (float*)alloc(2 * NB * 256 * 4);
    float* bias768 = (float*)alloc(3 * G3 * 4);
    float* Ax     = (float*)alloc((size_t)NN * DOUT * 4);
    _Float16* xp16 = (_Float16*)alloc((size_t)NN * G3 * 2);

    _Float16* node16 = (_Float16*)alloc((size_t)NN * DOUT * 2);
    _Float16* yA16   = (_Float16*)alloc((size_t)NN * DOUT * 2);
    _Float16* x16    = (_Float16*)alloc((size_t)NN * DOUT * 2);
    _Float16* yB16   = x16;  // alias: x16 dead after Ax GEMM, yB16 live later
    _Float16* WA16   = (_Float16*)alloc((size_t)256 * 256 * 2);
    _Float16* wih16[3];
    for (int l = 0; l < 3; ++l) wih16[l] = (_Float16*)alloc((size_t)G3 * 256 * 2);

    // --- CSR build + weight conversions + bias fold ---
    hipMemsetAsync(deg, 0, (size_t)3 * NN * 4, stream);    // deg+offs+cursor
    k_count<<<NE / 256, 256, 0, stream>>>(ei, deg);
    k_scan_offs<<<1, 1024, 0, stream>>>(deg, offs, dinv);
    k_fill<<<NE / 256, 256, 0, stream>>>(ei, offs, cursor, eidx);
    k_bself<<<1, 256, 0, stream>>>(WB, Bself);
    k_bias_fold<<<9, 256, 0, stream>>>(b_ih[0], b_hh[0], b_ih[1], b_hh[1],
                                       b_ih[2], b_hh[2], bias768);
    k_cvt_all<<<4736, 256, 0, stream>>>(x, WA, w_ih[0], w_ih[1], w_ih[2],
                                        x16, WA16, wih16[0], wih16[1], wih16[2]);

    // --- GCN ---
    {
        dim3 g(NN / 128, 256 / 128);
        k_gemm16<false><<<g, 256, 0, stream>>>(x16, WA16, nullptr, Ax, NN, 256);
    }
    k_gcn<<<NN, 256, 0, stream>>>(Ax, WB, edge_attr, ei, eidx, offs, deg, dinv,
                                  Bself, gcn_bias, node16);

    // --- GRU x3 (layer 2 fuses pooling+linear+softmax) ---
    const _Float16* in16 = node16;
    _Float16* y16_outs[3] = {yA16, yB16, yA16};
    for (int l = 0; l < 3; ++l) {
        dim3 g(NN / 128, G3 / 128);
        k_gemm16<true><<<g, 256, 0, stream>>>(in16, wih16[l], bias768 + l * G3,
                                              xp16, NN, G3);
        k_gru_scan<<<NB, 512, 0, stream>>>(xp16, w_hh[l], b_hh[l], y16_outs[l],
                                           hT, l, lin_W, lin_b, out);
        in16 = y16_outs[l];
    }
}